// Round 19
// baseline (328.640 us; speedup 1.0000x reference)
//
#include <hip/hip_runtime.h>

#define NB   4
#define SEQ  1024
#define MD   1024
#define NH   16
#define HD   64
#define FF   4096
#define NK   (NB*SEQ)
#define EPSF 1e-5f
#define QS   3072          // fused QKV row stride (bf16 elems)

typedef short short8 __attribute__((ext_vector_type(8)));
typedef float f32x4  __attribute__((ext_vector_type(4)));
typedef unsigned short u16;
typedef unsigned int u32;

__device__ __forceinline__ u16 f2bf(float x) {
    union { float f; unsigned u; } v; v.f = x;
    unsigned r = v.u + 0x7FFF + ((v.u >> 16) & 1);
    return (u16)(r >> 16);
}
__device__ __forceinline__ u16 f2bf_trunc(float x) {   // positive values
    union { float f; unsigned u; } v; v.f = x;
    return (u16)(v.u >> 16);
}
__device__ __forceinline__ float bf2f(u16 x) {
    union { unsigned u; float f; } v; v.u = ((unsigned)x) << 16;
    return v.f;
}
__device__ __forceinline__ void gload_lds16(const void* g, void* l) {
    __builtin_amdgcn_global_load_lds(
        (const __attribute__((address_space(1))) unsigned int*)g,
        (__attribute__((address_space(3))) unsigned int*)l,
        16, 0, 0);
}

// ---------------------------------------------------------------------------
// dec+enc fp32 -> bf16. Grid (4096, 2).
// ---------------------------------------------------------------------------
__global__ __launch_bounds__(256) void conv_bf16(const float* __restrict__ s0,
                                                 const float* __restrict__ s1,
                                                 u16* __restrict__ d0,
                                                 u16* __restrict__ d1) {
    const float* S = blockIdx.y ? s1 : s0;
    u16* D = blockIdx.y ? d1 : d0;
    const int i = blockIdx.x * 256 + threadIdx.x;
    float4 v = ((const float4*)S)[i];
    ushort4 o;
    o.x = f2bf(v.x); o.y = f2bf(v.y); o.z = f2bf(v.z); o.w = f2bf(v.w);
    ((ushort4*)D)[i] = o;
}

// ---------------------------------------------------------------------------
// Mask tile precompute for 128x128 tiles: per (n, qt128, jt128) -> class
// {0 empty, 1 partial, 2 full} + per-row 128-bit masks. Grid (8,8,4), blk 256.
// ---------------------------------------------------------------------------
__global__ __launch_bounds__(256) void mask_tiles(const int* __restrict__ mask,
                                                  int* __restrict__ cls,
                                                  u32* __restrict__ bits) {
    const int jt = blockIdx.x, qt = blockIdx.y, n = blockIdx.z;
    const int t = threadIdx.x;
    const int r = t >> 1, h2 = (t & 1) * 2;
    u32 bb[2];
#pragma unroll
    for (int sg = 0; sg < 2; ++sg) {
        const int* mp = &mask[((size_t)n * SEQ + qt * 128 + r) * SEQ + jt * 128 + (h2 + sg) * 32];
        u32 b = 0;
#pragma unroll
        for (int k = 0; k < 8; ++k) {
            int4 v = *(const int4*)(mp + k * 4);
            b |= (v.x ? 1u : 0u) << (k * 4 + 0);
            b |= (v.y ? 1u : 0u) << (k * 4 + 1);
            b |= (v.z ? 1u : 0u) << (k * 4 + 2);
            b |= (v.w ? 1u : 0u) << (k * 4 + 3);
        }
        bb[sg] = b;
    }
    const int tile = (n * 8 + qt) * 8 + jt;
    bits[((size_t)tile * 128 + r) * 4 + h2]     = bb[0];
    bits[((size_t)tile * 128 + r) * 4 + h2 + 1] = bb[1];
    const int nfull  = __syncthreads_count(bb[0] == 0xFFFFFFFFu && bb[1] == 0xFFFFFFFFu);
    const int nempty = __syncthreads_count(bb[0] == 0u && bb[1] == 0u);
    if (t == 0) cls[tile] = (nfull == 256) ? 2 : ((nempty == 256) ? 0 : 1);
}

// ---------------------------------------------------------------------------
// QKV weight repack (6 heads-major weights -> fused transposed buffers).
// ---------------------------------------------------------------------------
struct QkvArgs { const float* src[6]; u16* dst[6]; };

__global__ __launch_bounds__(256) void repack_qkv(QkvArgs a) {
    const int m0 = blockIdx.x * 64;
    const int h  = blockIdx.y;
    const int w  = blockIdx.z;
    const float* W = a.src[w];
    u16* BT = a.dst[w];
    const int t = threadIdx.x;
    __shared__ u16 Ts[64][72];

    const int r = t >> 4, c4 = (t & 15) * 4;
#pragma unroll
    for (int p = 0; p < 4; ++p) {
        const int row = r + p * 16;
        float4 v = *(const float4*)&W[((size_t)h * 1024 + m0 + row) * 64 + c4];
        Ts[row][c4] = f2bf(v.x); Ts[row][c4 + 1] = f2bf(v.y);
        Ts[row][c4 + 2] = f2bf(v.z); Ts[row][c4 + 3] = f2bf(v.w);
    }
    __syncthreads();
    const int d = t >> 2, j0 = (t & 3) * 16;
#pragma unroll
    for (int p = 0; p < 4; ++p) {
        ushort4 o;
        o.x = Ts[j0 + p * 4 + 0][d]; o.y = Ts[j0 + p * 4 + 1][d];
        o.z = Ts[j0 + p * 4 + 2][d]; o.w = Ts[j0 + p * 4 + 3][d];
        *(ushort4*)&BT[((size_t)h * 64 + d) * 1024 + m0 + j0 + p * 4] = o;
    }
}

// ---------------------------------------------------------------------------
// Flat weight repacks via descriptors. Grid (16,16,10).
// ---------------------------------------------------------------------------
struct FD { const float* src; int ss; u16* dst; int ds; };
struct FlatArgs { FD d[10]; };

__global__ __launch_bounds__(256) void repack_flat(FlatArgs fa) {
    FD u = fa.d[blockIdx.z];
    const int r0 = blockIdx.x * 64;
    const int c0 = blockIdx.y * 64;
    const int t  = threadIdx.x;
    __shared__ u16 Ts[64][72];

    const int r = t >> 4, c4 = (t & 15) * 4;
#pragma unroll
    for (int p = 0; p < 4; ++p) {
        const int row = r + p * 16;
        float4 v = *(const float4*)&u.src[(size_t)(r0 + row) * u.ss + c0 + c4];
        Ts[row][c4] = f2bf(v.x); Ts[row][c4 + 1] = f2bf(v.y);
        Ts[row][c4 + 2] = f2bf(v.z); Ts[row][c4 + 3] = f2bf(v.w);
    }
    __syncthreads();
    const int d = t >> 2, j0 = (t & 3) * 16;
#pragma unroll
    for (int p = 0; p < 4; ++p) {
        ushort4 o;
        o.x = Ts[j0 + p * 4 + 0][d]; o.y = Ts[j0 + p * 4 + 1][d];
        o.z = Ts[j0 + p * 4 + 2][d]; o.w = Ts[j0 + p * 4 + 3][d];
        *(ushort4*)&u.dst[(size_t)(c0 + d) * u.ds + r0 + j0 + p * 4] = o;
    }
}

// ---------------------------------------------------------------------------
// bf16 MFMA GEMM, 256x128 tile, 8 waves (4M x 2N), BK=64, 3-deep LDS pipeline,
// ONE barrier per K-tile + full register-fragment prefetch (round-9 verified).
// PARTIAL takes a second partial pointer via the VtOut slot (Wo/FFN2 SK=2).
// LDS = 3 x 48 KB = 144 KB dynamic, 1 block/CU. Grid (Nd/128, Md/256 [,SK]).
// ---------------------------------------------------------------------------
template<int OUT_BF16, int RELU, int BIAS3, int PARTIAL, int VT, int RESID>
__global__ __launch_bounds__(512, 2) void gemm256p(const u16* __restrict__ A,
                                                   const u16* __restrict__ A2,
                                                   int Astride,
                                                   const u16* __restrict__ BT,
                                                   int Bstride,
                                                   const float* __restrict__ b0,
                                                   const float* __restrict__ b1p,
                                                   const float* __restrict__ b2p,
                                                   const float* __restrict__ resid,
                                                   void* __restrict__ Cout,
                                                   u16* __restrict__ VtOut,
                                                   int Kd, int Nd, int swzW) {
    const int t  = threadIdx.x;
    const int wave = t >> 6, lane = t & 63;
    const int q = lane >> 4, l16 = lane & 15;
    const int wm = wave >> 1, wn = wave & 1;   // 4M x 2N wave grid, 64x64 out/wave-slot
    const int x7 = l16 & 7;

    // ---- bijective 2D-chunked XCD swizzle (dispatch id round-robins % 8) ----
    const int gx = gridDim.x;
    const int bid = blockIdx.x + blockIdx.y * gx;
    const int cpx = (gx * gridDim.y) >> 3;
    const int xcd = bid & 7;
    const int cc  = bid >> 3;
    const int regNX = gx / swzW;
    const int mtspan = cpx / swzW;
    const int nt = (xcd % regNX) * swzW + cc % swzW;
    const int mt = (xcd / regNX) * mtspan + cc / swzW;

    extern __shared__ __align__(16) char smem[];
    u16* As = (u16*)smem;                          // [3][256*64]
    u16* Bs = (u16*)(smem + 3 * 256 * 64 * 2);     // [3][128*64]

    const int row0 = mt * 256, col0 = nt * 128;
    const u16* Ause = (col0 < 1024) ? A : A2;
    const int kBase = PARTIAL ? blockIdx.z * Kd : 0;

    f32x4 acc[4][4];
#pragma unroll
    for (int r = 0; r < 4; ++r)
#pragma unroll
        for (int c = 0; c < 4; ++c) acc[r][c] = (f32x4)0.0f;

    const int lrow = lane >> 3;
    const int lcb  = lane & 7;

    // one part = 3 gload_lds (A 2 + B 1); a tile = 2 parts = 6 loads/thread
    auto stagePart = [&](int slot, int kk, int part) {
#pragma unroll
        for (int p = 0; p < 2; ++p) {
            const int rr = wave * 32 + (part * 2 + p) * 8 + lrow;   // 8w x 32 = 256 rows
            const int gcb = lcb ^ (rr & 7);
            gload_lds16(Ause + (size_t)(row0 + rr) * Astride + kk + gcb * 8,
                        As + slot * (256 * 64) + (wave * 32 + (part * 2 + p) * 8) * 64);
        }
        {
            const int rr = wave * 16 + part * 8 + lrow;             // 8w x 16 = 128 rows
            const int gcb = lcb ^ (rr & 7);
            gload_lds16(BT + (size_t)(col0 + rr) * Bstride + kk + gcb * 8,
                        Bs + slot * (128 * 64) + (wave * 16 + part * 8) * 64);
        }
    };

    const int nsteps = Kd / 64;
    // prologue: stage tiles 0 and 1 (12 loads in flight)
    stagePart(0, kBase, 0);      stagePart(0, kBase, 1);
    stagePart(1, kBase + 64, 0); stagePart(1, kBase + 64, 1);

    int st = 0, st2 = 2;
    for (int it = 0; it < nsteps; ++it) {
        if (it + 1 < nsteps) asm volatile("s_waitcnt vmcnt(6)" ::: "memory");
        else                 asm volatile("s_waitcnt vmcnt(0)" ::: "memory");
        __builtin_amdgcn_s_barrier();

        const u16* Ab = As + st * (256 * 64);
        const u16* Bb = Bs + st * (128 * 64);
        const int pb0 = q ^ x7;
        const int pb1 = (q + 4) ^ x7;

        short8 af0[4], bf0[4], af1[4], bf1[4];
#pragma unroll
        for (int r = 0; r < 4; ++r) {
            af0[r] = *(const short8*)&Ab[(wm * 64 + r * 16 + l16) * 64 + pb0 * 8];
            af1[r] = *(const short8*)&Ab[(wm * 64 + r * 16 + l16) * 64 + pb1 * 8];
        }
#pragma unroll
        for (int c = 0; c < 4; ++c) {
            bf0[c] = *(const short8*)&Bb[(wn * 64 + c * 16 + l16) * 64 + pb0 * 8];
            bf1[c] = *(const short8*)&Bb[(wn * 64 + c * 16 + l16) * 64 + pb1 * 8];
        }

        const bool pre = (it + 2 < nsteps);
        const int kk2 = kBase + (it + 2) * 64;
        if (pre) stagePart(st2, kk2, 0);

        __builtin_amdgcn_s_setprio(1);
#pragma unroll
        for (int r = 0; r < 4; ++r)
#pragma unroll
            for (int c = 0; c < 4; ++c)
                acc[r][c] = __builtin_amdgcn_mfma_f32_16x16x32_bf16(af0[r], bf0[c], acc[r][c], 0, 0, 0);
        __builtin_amdgcn_s_setprio(0);

        if (pre) stagePart(st2, kk2, 1);

        __builtin_amdgcn_s_setprio(1);
#pragma unroll
        for (int r = 0; r < 4; ++r)
#pragma unroll
            for (int c = 0; c < 4; ++c)
                acc[r][c] = __builtin_amdgcn_mfma_f32_16x16x32_bf16(af1[r], bf1[c], acc[r][c], 0, 0, 0);
        __builtin_amdgcn_s_setprio(0);

        st  = (st  == 2) ? 0 : st + 1;
        st2 = (st2 == 2) ? 0 : st2 + 1;
    }

    if (VT && col0 >= 2048) {
        // V section: write transposed into Vt[((n*16+h)*64+d)*1024 + k]
#pragma unroll
        for (int c = 0; c < 4; ++c) {
            const int col = col0 + wn * 64 + c * 16 + l16;
            const float bb = b2p[col & 1023];
            const int d = col & 63, hh = (col >> 6) & 15;
#pragma unroll
            for (int r = 0; r < 4; ++r) {
                const int row = row0 + wm * 64 + r * 16 + q * 4;
                const int nn = row >> 10, k = row & 1023;
                ushort4 o;
                o.x = f2bf(acc[r][c][0] + bb);
                o.y = f2bf(acc[r][c][1] + bb);
                o.z = f2bf(acc[r][c][2] + bb);
                o.w = f2bf(acc[r][c][3] + bb);
                *(ushort4*)&VtOut[((size_t)(nn * 16 + hh) * 64 + d) * 1024 + k] = o;
            }
        }
        return;
    }

    float* Pout = PARTIAL ? (blockIdx.z == 0 ? (float*)Cout : (float*)VtOut) : nullptr;

#pragma unroll
    for (int c = 0; c < 4; ++c) {
        const int col = col0 + wn * 64 + c * 16 + l16;
        float bb = 0.0f;
        if (!PARTIAL) {
            if (BIAS3) {
                const int sec = col >> 10;
                const float* bp = sec == 0 ? b0 : (sec == 1 ? b1p : b2p);
                bb = bp[col & 1023];
            } else {
                bb = b0[col];
            }
        }
#pragma unroll
        for (int r = 0; r < 4; ++r) {
#pragma unroll
            for (int reg = 0; reg < 4; ++reg) {
                const int row = row0 + wm * 64 + r * 16 + q * 4 + reg;
                float v = acc[r][c][reg] + bb;
                if (PARTIAL) {
                    Pout[(size_t)row * Nd + col] = acc[r][c][reg];
                } else {
                    if (RELU)  v = fmaxf(v, 0.0f);
                    if (RESID) v += resid[(size_t)row * Nd + col];
                    if (OUT_BF16) ((u16*)Cout)[(size_t)row * Nd + col] = f2bf(v);
                    else          ((float*)Cout)[(size_t)row * Nd + col] = v;
                }
            }
        }
    }
}

// ---------------------------------------------------------------------------
// MFMA flash attention v11: v10b (T14 reg-staging, P-half, 50 KB LDS) +
// KV-SPLIT x2 with the CORRECT launch bounds. Round-17 showed occupancy is
// GRID-limited (512 blocks = 2 blocks/CU); the split doubles the grid to
// 1024 -> 3 blocks/CU = 6 waves/SIMD (LDS-limited). Round-15/16 proved the
// partial/combine math and workspace correct; their regression was the
// (512,6) 40-VGPR spill (round-16 diagnosis), fixed here with (512,4).
// Blocks emit UNNORMALIZED bf16 O-partials + fp32 rowsums; combine is exact.
// jbeg/jend block-uniform (causal prefix) -> barriers safe.
// LDS 51200 B. Grid (NH, SEQ/128, NB*2).
// ---------------------------------------------------------------------------
#define PSTR 72
#define ATTN_LDS (128*64*2 + 64*128*2 + 8*16*PSTR*2)   // 16K + 16K + 18432 = 51200

__global__ __launch_bounds__(512, 4) void attn_mfma(const u16* __restrict__ QKV,
                                                    const u16* __restrict__ Vt,
                                                    const int* __restrict__ cls,
                                                    const u32* __restrict__ bits,
                                                    u16* __restrict__ Op0,
                                                    u16* __restrict__ Op1,
                                                    float* __restrict__ Lp0,
                                                    float* __restrict__ Lp1) {
    const int h  = blockIdx.x;     // head -> XCD (bid&7 = h&7)
    const int zz = blockIdx.z;
    const int n  = zz >> 1;
    const int kh = zz & 1;         // KV half
    const int qt = (n & 2) ? 7 - (int)blockIdx.y : (int)blockIdx.y;  // causal balance
    const int t  = threadIdx.x;
    const int wave = t >> 6;       // 0..7
    const int lane = t & 63;
    const int quad = lane >> 4;
    const int l16  = lane & 15;
    const int sw   = wave >> 2;    // q-subtile
    const int wq   = wave & 3;     // sub-wave slot within the subtile

    extern __shared__ __align__(16) char smem[];
    u16* Ks = (u16*)smem;                          // [key][d]  128x64, 16 KB
    u16* Vs = (u16*)(smem + 128 * 64 * 2);         // [d][key]  64x128, 16 KB
    u16* Pw = (u16*)(smem + 128 * 64 * 2 + 64 * 128 * 2) + wave * 16 * PSTR; // wave-private P (64 keys)

    u16*   Op = kh ? Op1 : Op0;
    float* Lp = kh ? Lp1 : Lp0;

    const int bh = n * NH + h;
    const int i0 = qt * 128;

    // tile classes; actives form a prefix (causal) -> na block-uniform
    int cl[8];
    if (cls) {
        const int* cp = &cls[(n * 8 + qt) * 8];
#pragma unroll
        for (int j = 0; j < 8; ++j) cl[j] = cp[j];
    } else {
#pragma unroll
        for (int j = 0; j < 8; ++j) cl[j] = 2;
    }
    int na = 0;
#pragma unroll
    for (int j = 0; j < 8; ++j) if (cl[j] != 0) ++na;
    const int half = (na + 1) >> 1;
    const int jbeg = kh ? half : 0;
    const int jend = kh ? na : half;

    // Q A-fragment for this wave's 16 q-rows, pre-scaled by 0.125*log2e
    short8 qf[2];
    {
        const u16* qrow = QKV + ((size_t)n * SEQ + i0 + sw * 64 + wq * 16 + l16) * QS + h * 64 + quad * 8;
        short8 a = *(const short8*)(qrow);
        short8 b = *(const short8*)(qrow + 32);
#pragma unroll
        for (int j = 0; j < 8; ++j) {
            qf[0][j] = (short)f2bf(bf2f((u16)a[j]) * 0.18033688f);
            qf[1][j] = (short)f2bf(bf2f((u16)b[j]) * 0.18033688f);
        }
    }

    f32x4 O[4];
#pragma unroll
    for (int d = 0; d < 4; ++d) O[d] = (f32x4)0.0f;
    float lrow[4] = {};

    const int x7 = l16 & 7;

    // ---- T14 reg-staging maps (LDS content: Ks[r][c^(r&7)], Vs[r][c^(r&15)]) ----
    const int kr  = wave * 16 + (lane & 15);          // K row 0..127
    const int ck0 = (lane >> 4) * 2;                  // K col-blocks {ck0, ck0+1} of 8
    const int vr  = wave * 8 + (lane >> 3);           // V row 0..63
    const int cv0 = (lane & 7) * 2;                   // V col-blocks {cv0, cv0+1} of 16
    u16* kdst0 = &Ks[kr * 64 + ((ck0)     ^ (kr & 7)) * 8];
    u16* kdst1 = &Ks[kr * 64 + ((ck0 + 1) ^ (kr & 7)) * 8];
    u16* vdst0 = &Vs[vr * 128 + ((cv0)     ^ (vr & 15)) * 8];
    u16* vdst1 = &Vs[vr * 128 + ((cv0 + 1) ^ (vr & 15)) * 8];
    const u16* kgbase = QKV + ((size_t)n * SEQ + kr) * QS + 1024 + h * 64 + ck0 * 8;
    const u16* vgbase = Vt + ((size_t)bh * HD + vr) * SEQ + cv0 * 8;

    short8 krg0, krg1, vrg0, vrg1;
    auto loadT = [&](int j) {
        const u16* kp = kgbase + (size_t)j * 128 * QS;
        krg0 = *(const short8*)(kp);
        krg1 = *(const short8*)(kp + 8);
        const u16* vp = vgbase + j * 128;
        vrg0 = *(const short8*)(vp);
        vrg1 = *(const short8*)(vp + 8);
    };
    auto writeT = [&]() {
        *(short8*)kdst0 = krg0;
        *(short8*)kdst1 = krg1;
        *(short8*)vdst0 = vrg0;
        *(short8*)vdst1 = vrg1;
    };

    if (jbeg < jend) {
        loadT(jbeg);
        writeT();
        asm volatile("s_waitcnt lgkmcnt(0)" ::: "memory");
        __builtin_amdgcn_s_barrier();          // first tile writes visible

        for (int j = jbeg; j < jend; ++j) {
            const int c = cl[j];
            if (j + 1 < jend) loadT(j + 1);    // in flight across the whole compute

            // ---- S = Q K^T ----
            f32x4 S[8];
#pragma unroll
            for (int sub = 0; sub < 8; ++sub) {
                S[sub] = (f32x4)0.0f;
                const int row = sub * 16 + l16;
                short8 k0 = *(const short8*)&Ks[row * 64 + ((quad ^ x7) * 8)];
                S[sub] = __builtin_amdgcn_mfma_f32_16x16x32_bf16(qf[0], k0, S[sub], 0, 0, 0);
                short8 k1 = *(const short8*)&Ks[row * 64 + (((4 + quad) ^ x7) * 8)];
                S[sub] = __builtin_amdgcn_mfma_f32_16x16x32_bf16(qf[1], k1, S[sub], 0, 0, 0);
            }

            if (c == 1) {
#pragma unroll
                for (int reg = 0; reg < 4; ++reg) {
                    const int row = sw * 64 + wq * 16 + quad * 4 + reg;
                    const uint4 mm = *(const uint4*)&bits[((size_t)((n * 8 + qt) * 8 + j) * 128 + row) * 4];
#pragma unroll
                    for (int sub = 0; sub < 8; ++sub) {
                        const u32 seg = (sub >> 1) == 0 ? mm.x : (sub >> 1) == 1 ? mm.y : (sub >> 1) == 2 ? mm.z : mm.w;
                        if (!((seg >> ((sub & 1) * 16 + l16)) & 1u)) S[sub][reg] = -1e30f;
                    }
                }
            }

            // ---- softmax + PV in two 64-key halves (P buffer holds 64 keys) ----
            float rst[4] = {0.0f, 0.0f, 0.0f, 0.0f};
#pragma unroll
            for (int h2 = 0; h2 < 2; ++h2) {
#pragma unroll
                for (int reg = 0; reg < 4; ++reg) {
#pragma unroll
                    for (int s4 = 0; s4 < 4; ++s4) {
                        float e = exp2f(S[h2 * 4 + s4][reg]);    // masked: exp2(-1e30) = 0
                        Pw[(quad * 4 + reg) * PSTR + s4 * 16 + l16] = f2bf_trunc(e);
                        rst[reg] += e;
                    }
                }
                short8 pa[2];
#pragma unroll
                for (int ks = 0; ks < 2; ++ks)
                    pa[ks] = *(const short8*)&Pw[l16 * PSTR + ks * 32 + quad * 8];
#pragma unroll
                for (int d = 0; d < 4; ++d) {
                    const int row = d * 16 + l16;
#pragma unroll
                    for (int ks = 0; ks < 2; ++ks) {
                        const int kg = h2 * 2 + ks;
                        short8 vb = *(const short8*)&Vs[row * 128 + (((kg * 4 + quad) ^ l16) & 15) * 8];
                        O[d] = __builtin_amdgcn_mfma_f32_16x16x32_bf16(pa[ks], vb, O[d], 0, 0, 0);
                    }
                }
            }
#pragma unroll
            for (int reg = 0; reg < 4; ++reg) {
                float rs = rst[reg];
                rs += __shfl_xor(rs, 1);
                rs += __shfl_xor(rs, 2);
                rs += __shfl_xor(rs, 4);
                rs += __shfl_xor(rs, 8);
                lrow[reg] += rs;
            }

            __builtin_amdgcn_s_barrier();      // all waves done READING tile j LDS
            if (j + 1 < jend) {
                writeT();
                asm volatile("s_waitcnt lgkmcnt(0)" ::: "memory");
            }
            __builtin_amdgcn_s_barrier();      // tile j+1 writes visible
        }
    }

    // ---- write UNNORMALIZED bf16 partial O + fp32 partial rowsums ----
#pragma unroll
    for (int d = 0; d < 4; ++d) {
#pragma unroll
        for (int reg = 0; reg < 4; ++reg) {
            const int row = i0 + sw * 64 + wq * 16 + quad * 4 + reg;
            const int col = h * 64 + d * 16 + l16;
            Op[((size_t)n * SEQ + row) * MD + col] = f2bf(O[d][reg]);
        }
    }
    if (l16 == 0) {
#pragma unroll
        for (int reg = 0; reg < 4; ++reg) {
            const int row = i0 + sw * 64 + wq * 16 + quad * 4 + reg;
            Lp[((size_t)n * NH + h) * SEQ + row] = lrow[reg];
        }
    }
}

// ---------------------------------------------------------------------------
// Combine KV-split partials: Y[row][col] = (O0+O1)/(l0+l1) -> bf16 into the
// consumed Q section of QKVb (stride QS). Grid (NK), 256 thr.
// ---------------------------------------------------------------------------
__global__ __launch_bounds__(256) void attn_combine(const u16* __restrict__ Op0,
                                                    const u16* __restrict__ Op1,
                                                    const float* __restrict__ Lp0,
                                                    const float* __restrict__ Lp1,
                                                    u16* __restrict__ Yout) {
    const int row = blockIdx.x;
    const int t = threadIdx.x;
    const int c = t * 4;
    const int hh = c >> 6;
    const size_t lidx = ((size_t)(row >> 10) * NH + hh) * SEQ + (row & 1023);
    const float inv = 1.0f / (Lp0[lidx] + Lp1[lidx]);
    const ushort4 a = *(const ushort4*)&Op0[(size_t)row * MD + c];
    const ushort4 b = *(const ushort4*)&Op1[(size_t)row * MD + c];
    ushort4 o;
    o.x = f2bf((bf2f(a.x) + bf2f(b.x)) * inv);
    o.y = f2bf((bf2f(a.y) + bf2f(b.y)) * inv);
    o.z = f2bf((bf2f(a.z) + bf2f(b.z)) * inv);
    o.w = f2bf((bf2f(a.w) + bf2f(b.w)) * inv);
    *(ushort4*)&Yout[(size_t)row * QS + c] = o;
}

// ---------------------------------------------------------------------------
// Fused: LN( p0 + p1 + bias + resid ) -> fp32 out + optional bf16 out.
// In-place rule: Y/Yb may alias p0/p1/resid ROW-wise only.
// ---------------------------------------------------------------------------
__global__ __launch_bounds__(256) void ln_fused2(const float* __restrict__ p0,
                                                 const float* __restrict__ p1,
                                                 const float* __restrict__ bias,
                                                 const float* __restrict__ resid,
                                                 const float* __restrict__ g,
                                                 const float* __restrict__ be,
                                                 float* __restrict__ Y,
                                                 u16* __restrict__ Yb) {
    const int row = blockIdx.x;
    const int t = threadIdx.x;
    __shared__ float red[256];

    const float4 a = ((const float4*)(p0 + (size_t)row * MD))[t];
    const float4 b = ((const float4*)(p1 + (size_t)row * MD))[t];
    const float4 r = ((const float4*)(resid + (size_t)row * MD))[t];
    const float4 bi = ((const float4*)bias)[t];
    float4 v;
    v.x = a.x + b.x + r.x + bi.x;
    v.y = a.y + b.y + r.y + bi.y;
    v.z = a.z + b.z + r.z + bi.z;
    v.w = a.w + b.w + r.w + bi.w;

    red[t] = v.x + v.y + v.z + v.w;
    __syncthreads();
    for (int s2 = 128; s2 > 0; s2 >>= 1) {
        if (t < s2) red[t] += red[t + s2];
        __syncthreads();
    }
    const float mu = red[0] * (1.0f / MD);
    __syncthreads();

    float dx = v.x - mu, dy = v.y - mu, dz = v.z - mu, dw = v.w - mu;
    red[t] = dx * dx + dy * dy + dz * dz + dw * dw;
    __syncthreads();
    for (int s2 = 128; s2 > 0; s2 >>= 1) {
        if (t < s2) red[t] += red[t + s2];
        __syncthreads();
    }
    const float var = red[0] * (1.0f / MD);
    const float rs = rsqrtf(var + EPSF);

    const float4 gv = ((const float4*)g)[t];
    const float4 bv = ((const float4*)be)[t];
    float4 o;
    o.x = dx * rs * gv.x + bv.x;
    o.y = dy * rs * gv.y + bv.y;
    o.z = dz * rs * gv.z + bv.z;
    o.w = dw * rs * gv.w + bv.w;
    if (Y) ((float4*)(Y + (size_t)row * MD))[t] = o;
    if (Yb) {
        ushort4 ob;
        ob.x = f2bf(o.x); ob.y = f2bf(o.y); ob.z = f2bf(o.z); ob.w = f2bf(o.w);
        ((ushort4*)(Yb + (size_t)row * MD))[t] = ob;
    }
}

// ---------------------------------------------------------------------------
extern "C" void kernel_launch(void* const* d_in, const int* in_sizes, int n_in,
                              void* d_out, int out_size, void* d_ws, size_t ws_size,
                              hipStream_t stream) {
    const float* dec  = (const float*)d_in[0];
    const float* enc  = (const float*)d_in[1];
    const int*   mask = (const int*)d_in[2];
    const float* Wq_s = (const float*)d_in[3];
    const float* bq_s = (const float*)d_in[4];
    const float* Wk_s = (const float*)d_in[5];
    const float* bk_s = (const float*)d_in[6];
    const float* Wv_s = (const float*)d_in[7];
    const float* bv_s = (const float*)d_in[8];
    const float* Wo_s = (const float*)d_in[9];
    const float* bo_s = (const float*)d_in[10];
    const float* Wq_c = (const float*)d_in[11];
    const float* bq_c = (const float*)d_in[12];
    const float* Wk_c = (const float*)d_in[13];
    const float* bk_c = (const float*)d_in[14];
    const float* Wv_c = (const float*)d_in[15];
    const float* bv_c = (const float*)d_in[16];
    const float* Wo_c = (const float*)d_in[17];
    const float* bo_c = (const float*)d_in[18];
    const float* W1   = (const float*)d_in[19];
    const float* b1   = (const float*)d_in[20];
    const float* W2   = (const float*)d_in[21];
    const float* b2   = (const float*)d_in[22];
    const float* g1   = (const float*)d_in[23];
    const float* be1  = (const float*)d_in[24];
    const float* g2   = (const float*)d_in[25];
    const float* be2  = (const float*)d_in[26];
    const float* g3   = (const float*)d_in[27];
    const float* be3  = (const float*)d_in[28];

    char* wsb = (char*)d_ws;
    const size_t MB = 1u << 20;
    u16*   decb  = (u16*)(wsb + 0 * MB);
    u16*   O2b   = (u16*)(wsb + 0 * MB);
    u16*   encb  = (u16*)(wsb + 8 * MB);
    u16*   WqkvsT= (u16*)(wsb + 16 * MB);
    u16*   WqkvcT= (u16*)(wsb + 22 * MB);
    u16*   WosT  = (u16*)(wsb + 28 * MB);
    u16*   WocT  = (u16*)(wsb + 30 * MB);
    u16*   W1T   = (u16*)(wsb + 32 * MB);
    u16*   W2T   = (u16*)(wsb + 40 * MB);
    u16*   QKVb  = (u16*)(wsb + 48 * MB);
    u16*   Vt    = (u16*)(wsb + 72 * MB);
    u16*   Hb    = (u16*)(wsb + 48 * MB);
    int*   mcls  = (int*)(wsb + 80 * MB);
    u32*   mbits = (u32*)(wsb + 80 * MB + 64 * 1024);
    float* P0    = (float*)(wsb + 80 * MB);    // Wo partial 0 (both passes)
    float* O2    = (float*)(wsb + 96 * MB);    // p1-self lands here, LN1 in-place
    float* O4    = (float*)(wsb + 96 * MB);    // LN2 in-place over O2
    float* P1c   = (float*)(wsb + 0 * MB);     // Wo-cross partial 1
    u16*   O4b   = (u16*)(wsb + 16 * MB);
    float* FP    = (float*)(wsb + 0 * MB);     // FFN2 partials: z0 0-16, z1 16-32
    // attn KV-split partials (lifetimes verified in round 15, passed)
    u16*   OpS0  = (u16*)(wsb + 96 * MB);      // self Opart0 (O2 slot, dead until Wo)
    u16*   OpC0  = (u16*)(wsb + 0 * MB);       // cross Opart0 (O2b dead after QKV-c)
    u16*   OpD   = (u16*)d_out;                // Opart1 both passes (d_out scratch)
    float* LpA   = (float*)(wsb + 84 * MB);    // rowsum partial 0 (past mbits)
    float* LpB   = (float*)(wsb + 84 * MB + 256 * 1024);

    dim3 blk(256);
    dim3 blkA(512);
    dim3 blkG(512);
    dim3 gConv(NK * MD / 4 / 256, 2);
    dim3 gMask(8, 8, 4);
    dim3 gQkvW(16, 16, 6);
    dim3 gFlatW(16, 16, 10);
    dim3 gAttn(NH, SEQ / 128, NB * 2);       // x=h -> XCD=h&7; z = n*2+kh (KV split)
    dim3 gQKV(QS / 128, NK / 256);           // (24,16): swzW=6
    dim3 gWo(MD / 128, NK / 256, 2);         // (8,16,2): Wo SK=2, full chip
    dim3 gF1(FF / 128, NK / 256);            // (32,16): swzW=8
    dim3 gF2(MD / 128, NK / 256, 2);         // (8,16,2): swzW=2
    const int GP_LDS = 3 * (256 * 64 + 128 * 64) * 2;   // 144 KB (3-slot pipeline)

    // ---- converts + repacks + mask precompute ----
    conv_bf16<<<gConv, blk, 0, stream>>>(dec, enc, decb, encb);
    mask_tiles<<<gMask, blk, 0, stream>>>(mask, mcls, mbits);

    QkvArgs qa;
    qa.src[0] = Wq_s; qa.src[1] = Wk_s; qa.src[2] = Wv_s;
    qa.src[3] = Wq_c; qa.src[4] = Wk_c; qa.src[5] = Wv_c;
    qa.dst[0] = WqkvsT;                 qa.dst[1] = WqkvsT + (size_t)1024 * 1024;
    qa.dst[2] = WqkvsT + (size_t)2048 * 1024;
    qa.dst[3] = WqkvcT;                 qa.dst[4] = WqkvcT + (size_t)1024 * 1024;
    qa.dst[5] = WqkvcT + (size_t)2048 * 1024;
    repack_qkv<<<gQkvW, blk, 0, stream>>>(qa);

    FlatArgs fa;
    fa.d[0] = { Wo_s, 1024, WosT, 1024 };
    fa.d[1] = { Wo_c, 1024, WocT, 1024 };
    for (int u = 0; u < 4; ++u)
        fa.d[2 + u] = { W1 + (size_t)u * 1024, 4096, W1T + (size_t)u * 1024 * 1024, 1024 };
    for (int u = 0; u < 4; ++u)
        fa.d[6 + u] = { W2 + (size_t)u * 1024 * 1024, 1024, W2T + (size_t)u * 1024, 4096 };
    repack_flat<<<gFlatW, blk, 0, stream>>>(fa);

    // ---- self attention ----
    gemm256p<1, 0, 1, 0, 1, 0><<<gQKV, blkG, GP_LDS, stream>>>(decb, decb, MD, WqkvsT, MD, bq_s, bk_s, bv_s, nullptr, QKVb, Vt, MD, QS, 6);
    attn_mfma<<<gAttn, blkA, ATTN_LDS, stream>>>(QKVb, Vt, mcls, mbits, OpS0, OpD, LpA, LpB);
    attn_combine<<<NK, blk, 0, stream>>>(OpS0, OpD, LpA, LpB, QKVb);
    gemm256p<0, 0, 0, 1, 0, 0><<<gWo, blkG, GP_LDS, stream>>>(QKVb, QKVb, QS, WosT, MD, nullptr, nullptr, nullptr, nullptr, P0, (u16*)O2, MD / 2, MD, 2);
    ln_fused2<<<NK, blk, 0, stream>>>(P0, O2, bo_s, dec, g1, be1, O2, O2b);   // in-place over p1

    // ---- cross attention ----
    gemm256p<1, 0, 1, 0, 1, 0><<<gQKV, blkG, GP_LDS, stream>>>(O2b, encb, MD, WqkvcT, MD, bq_c, bk_c, bv_c, nullptr, QKVb, Vt, MD, QS, 6);
    attn_mfma<<<gAttn, blkA, ATTN_LDS, stream>>>(QKVb, Vt, nullptr, nullptr, OpC0, OpD, LpA, LpB);
    attn_combine<<<NK, blk, 0, stream>>>(OpC0, OpD, LpA, LpB, QKVb);
    gemm256p<0, 0, 0, 1, 0, 0><<<gWo, blkG, GP_LDS, stream>>>(QKVb, QKVb, QS, WocT, MD, nullptr, nullptr, nullptr, nullptr, P0, (u16*)P1c, MD / 2, MD, 2);
    ln_fused2<<<NK, blk, 0, stream>>>(P0, P1c, bo_c, O2, g2, be2, O4, O4b);  // Y in-place over resid

    // ---- feed-forward (FFN2 split-K=2; epilogue fused into LN) ----
    gemm256p<1, 1, 0, 0, 0, 0><<<gF1, blkG, GP_LDS, stream>>>(O4b, O4b, MD, W1T, MD, b1, nullptr, nullptr, nullptr, Hb, nullptr, MD, FF, 8);
    gemm256p<0, 0, 0, 1, 0, 0><<<gF2, blkG, GP_LDS, stream>>>(Hb, Hb, FF, W2T, FF, nullptr, nullptr, nullptr, nullptr, FP, (u16*)(FP + (size_t)NK * MD), FF / 2, MD, 2);
    ln_fused2<<<NK, blk, 0, stream>>>(FP, FP + (size_t)NK * MD, b2, O4, g3, be3, (float*)d_out, nullptr);
}

// Round 20
// 310.540 us; speedup vs baseline: 1.0583x; 1.0583x over previous
//
#include <hip/hip_runtime.h>

#define NB   4
#define SEQ  1024
#define MD   1024
#define NH   16
#define HD   64
#define FF   4096
#define NK   (NB*SEQ)
#define EPSF 1e-5f
#define QS   3072          // fused QKV row stride (bf16 elems)

typedef short short8 __attribute__((ext_vector_type(8)));
typedef float f32x4  __attribute__((ext_vector_type(4)));
typedef unsigned short u16;
typedef unsigned int u32;

__device__ __forceinline__ u16 f2bf(float x) {
    union { float f; unsigned u; } v; v.f = x;
    unsigned r = v.u + 0x7FFF + ((v.u >> 16) & 1);
    return (u16)(r >> 16);
}
__device__ __forceinline__ u16 f2bf_trunc(float x) {   // positive values
    union { float f; unsigned u; } v; v.f = x;
    return (u16)(v.u >> 16);
}
__device__ __forceinline__ float bf2f(u16 x) {
    union { unsigned u; float f; } v; v.u = ((unsigned)x) << 16;
    return v.f;
}
__device__ __forceinline__ void gload_lds16(const void* g, void* l) {
    __builtin_amdgcn_global_load_lds(
        (const __attribute__((address_space(1))) unsigned int*)g,
        (__attribute__((address_space(3))) unsigned int*)l,
        16, 0, 0);
}

// ---------------------------------------------------------------------------
// dec+enc fp32 -> bf16. Grid (4096, 2).
// ---------------------------------------------------------------------------
__global__ __launch_bounds__(256) void conv_bf16(const float* __restrict__ s0,
                                                 const float* __restrict__ s1,
                                                 u16* __restrict__ d0,
                                                 u16* __restrict__ d1) {
    const float* S = blockIdx.y ? s1 : s0;
    u16* D = blockIdx.y ? d1 : d0;
    const int i = blockIdx.x * 256 + threadIdx.x;
    float4 v = ((const float4*)S)[i];
    ushort4 o;
    o.x = f2bf(v.x); o.y = f2bf(v.y); o.z = f2bf(v.z); o.w = f2bf(v.w);
    ((ushort4*)D)[i] = o;
}

// ---------------------------------------------------------------------------
// Mask tile precompute for 128x128 tiles: per (n, qt128, jt128) -> class
// {0 empty, 1 partial, 2 full} + per-row 128-bit masks. Grid (8,8,4), blk 256.
// ---------------------------------------------------------------------------
__global__ __launch_bounds__(256) void mask_tiles(const int* __restrict__ mask,
                                                  int* __restrict__ cls,
                                                  u32* __restrict__ bits) {
    const int jt = blockIdx.x, qt = blockIdx.y, n = blockIdx.z;
    const int t = threadIdx.x;
    const int r = t >> 1, h2 = (t & 1) * 2;
    u32 bb[2];
#pragma unroll
    for (int sg = 0; sg < 2; ++sg) {
        const int* mp = &mask[((size_t)n * SEQ + qt * 128 + r) * SEQ + jt * 128 + (h2 + sg) * 32];
        u32 b = 0;
#pragma unroll
        for (int k = 0; k < 8; ++k) {
            int4 v = *(const int4*)(mp + k * 4);
            b |= (v.x ? 1u : 0u) << (k * 4 + 0);
            b |= (v.y ? 1u : 0u) << (k * 4 + 1);
            b |= (v.z ? 1u : 0u) << (k * 4 + 2);
            b |= (v.w ? 1u : 0u) << (k * 4 + 3);
        }
        bb[sg] = b;
    }
    const int tile = (n * 8 + qt) * 8 + jt;
    bits[((size_t)tile * 128 + r) * 4 + h2]     = bb[0];
    bits[((size_t)tile * 128 + r) * 4 + h2 + 1] = bb[1];
    const int nfull  = __syncthreads_count(bb[0] == 0xFFFFFFFFu && bb[1] == 0xFFFFFFFFu);
    const int nempty = __syncthreads_count(bb[0] == 0u && bb[1] == 0u);
    if (t == 0) cls[tile] = (nfull == 256) ? 2 : ((nempty == 256) ? 0 : 1);
}

// ---------------------------------------------------------------------------
// QKV weight repack (6 heads-major weights -> fused transposed buffers).
// ---------------------------------------------------------------------------
struct QkvArgs { const float* src[6]; u16* dst[6]; };

__global__ __launch_bounds__(256) void repack_qkv(QkvArgs a) {
    const int m0 = blockIdx.x * 64;
    const int h  = blockIdx.y;
    const int w  = blockIdx.z;
    const float* W = a.src[w];
    u16* BT = a.dst[w];
    const int t = threadIdx.x;
    __shared__ u16 Ts[64][72];

    const int r = t >> 4, c4 = (t & 15) * 4;
#pragma unroll
    for (int p = 0; p < 4; ++p) {
        const int row = r + p * 16;
        float4 v = *(const float4*)&W[((size_t)h * 1024 + m0 + row) * 64 + c4];
        Ts[row][c4] = f2bf(v.x); Ts[row][c4 + 1] = f2bf(v.y);
        Ts[row][c4 + 2] = f2bf(v.z); Ts[row][c4 + 3] = f2bf(v.w);
    }
    __syncthreads();
    const int d = t >> 2, j0 = (t & 3) * 16;
#pragma unroll
    for (int p = 0; p < 4; ++p) {
        ushort4 o;
        o.x = Ts[j0 + p * 4 + 0][d]; o.y = Ts[j0 + p * 4 + 1][d];
        o.z = Ts[j0 + p * 4 + 2][d]; o.w = Ts[j0 + p * 4 + 3][d];
        *(ushort4*)&BT[((size_t)h * 64 + d) * 1024 + m0 + j0 + p * 4] = o;
    }
}

// ---------------------------------------------------------------------------
// Flat weight repacks via descriptors. Grid (16,16,10).
// ---------------------------------------------------------------------------
struct FD { const float* src; int ss; u16* dst; int ds; };
struct FlatArgs { FD d[10]; };

__global__ __launch_bounds__(256) void repack_flat(FlatArgs fa) {
    FD u = fa.d[blockIdx.z];
    const int r0 = blockIdx.x * 64;
    const int c0 = blockIdx.y * 64;
    const int t  = threadIdx.x;
    __shared__ u16 Ts[64][72];

    const int r = t >> 4, c4 = (t & 15) * 4;
#pragma unroll
    for (int p = 0; p < 4; ++p) {
        const int row = r + p * 16;
        float4 v = *(const float4*)&u.src[(size_t)(r0 + row) * u.ss + c0 + c4];
        Ts[row][c4] = f2bf(v.x); Ts[row][c4 + 1] = f2bf(v.y);
        Ts[row][c4 + 2] = f2bf(v.z); Ts[row][c4 + 3] = f2bf(v.w);
    }
    __syncthreads();
    const int d = t >> 2, j0 = (t & 3) * 16;
#pragma unroll
    for (int p = 0; p < 4; ++p) {
        ushort4 o;
        o.x = Ts[j0 + p * 4 + 0][d]; o.y = Ts[j0 + p * 4 + 1][d];
        o.z = Ts[j0 + p * 4 + 2][d]; o.w = Ts[j0 + p * 4 + 3][d];
        *(ushort4*)&u.dst[(size_t)(c0 + d) * u.ds + r0 + j0 + p * 4] = o;
    }
}

// ---------------------------------------------------------------------------
// bf16 MFMA GEMM, 256x128 tile, 8 waves (4M x 2N), BK=64, 3-deep LDS pipeline,
// ONE barrier per K-tile + full register-fragment prefetch (round-9 verified).
// PARTIAL takes a second partial pointer via the VtOut slot (Wo/FFN2 SK=2).
// LDS = 3 x 48 KB = 144 KB dynamic, 1 block/CU. Grid (Nd/128, Md/256 [,SK]).
// ---------------------------------------------------------------------------
template<int OUT_BF16, int RELU, int BIAS3, int PARTIAL, int VT, int RESID>
__global__ __launch_bounds__(512, 2) void gemm256p(const u16* __restrict__ A,
                                                   const u16* __restrict__ A2,
                                                   int Astride,
                                                   const u16* __restrict__ BT,
                                                   int Bstride,
                                                   const float* __restrict__ b0,
                                                   const float* __restrict__ b1p,
                                                   const float* __restrict__ b2p,
                                                   const float* __restrict__ resid,
                                                   void* __restrict__ Cout,
                                                   u16* __restrict__ VtOut,
                                                   int Kd, int Nd, int swzW) {
    const int t  = threadIdx.x;
    const int wave = t >> 6, lane = t & 63;
    const int q = lane >> 4, l16 = lane & 15;
    const int wm = wave >> 1, wn = wave & 1;   // 4M x 2N wave grid, 64x64 out/wave-slot
    const int x7 = l16 & 7;

    // ---- bijective 2D-chunked XCD swizzle (dispatch id round-robins % 8) ----
    const int gx = gridDim.x;
    const int bid = blockIdx.x + blockIdx.y * gx;
    const int cpx = (gx * gridDim.y) >> 3;
    const int xcd = bid & 7;
    const int cc  = bid >> 3;
    const int regNX = gx / swzW;
    const int mtspan = cpx / swzW;
    const int nt = (xcd % regNX) * swzW + cc % swzW;
    const int mt = (xcd / regNX) * mtspan + cc / swzW;

    extern __shared__ __align__(16) char smem[];
    u16* As = (u16*)smem;                          // [3][256*64]
    u16* Bs = (u16*)(smem + 3 * 256 * 64 * 2);     // [3][128*64]

    const int row0 = mt * 256, col0 = nt * 128;
    const u16* Ause = (col0 < 1024) ? A : A2;
    const int kBase = PARTIAL ? blockIdx.z * Kd : 0;

    f32x4 acc[4][4];
#pragma unroll
    for (int r = 0; r < 4; ++r)
#pragma unroll
        for (int c = 0; c < 4; ++c) acc[r][c] = (f32x4)0.0f;

    const int lrow = lane >> 3;
    const int lcb  = lane & 7;

    // one part = 3 gload_lds (A 2 + B 1); a tile = 2 parts = 6 loads/thread
    auto stagePart = [&](int slot, int kk, int part) {
#pragma unroll
        for (int p = 0; p < 2; ++p) {
            const int rr = wave * 32 + (part * 2 + p) * 8 + lrow;   // 8w x 32 = 256 rows
            const int gcb = lcb ^ (rr & 7);
            gload_lds16(Ause + (size_t)(row0 + rr) * Astride + kk + gcb * 8,
                        As + slot * (256 * 64) + (wave * 32 + (part * 2 + p) * 8) * 64);
        }
        {
            const int rr = wave * 16 + part * 8 + lrow;             // 8w x 16 = 128 rows
            const int gcb = lcb ^ (rr & 7);
            gload_lds16(BT + (size_t)(col0 + rr) * Bstride + kk + gcb * 8,
                        Bs + slot * (128 * 64) + (wave * 16 + part * 8) * 64);
        }
    };

    const int nsteps = Kd / 64;
    // prologue: stage tiles 0 and 1 (12 loads in flight)
    stagePart(0, kBase, 0);      stagePart(0, kBase, 1);
    stagePart(1, kBase + 64, 0); stagePart(1, kBase + 64, 1);

    int st = 0, st2 = 2;
    for (int it = 0; it < nsteps; ++it) {
        if (it + 1 < nsteps) asm volatile("s_waitcnt vmcnt(6)" ::: "memory");
        else                 asm volatile("s_waitcnt vmcnt(0)" ::: "memory");
        __builtin_amdgcn_s_barrier();

        const u16* Ab = As + st * (256 * 64);
        const u16* Bb = Bs + st * (128 * 64);
        const int pb0 = q ^ x7;
        const int pb1 = (q + 4) ^ x7;

        short8 af0[4], bf0[4], af1[4], bf1[4];
#pragma unroll
        for (int r = 0; r < 4; ++r) {
            af0[r] = *(const short8*)&Ab[(wm * 64 + r * 16 + l16) * 64 + pb0 * 8];
            af1[r] = *(const short8*)&Ab[(wm * 64 + r * 16 + l16) * 64 + pb1 * 8];
        }
#pragma unroll
        for (int c = 0; c < 4; ++c) {
            bf0[c] = *(const short8*)&Bb[(wn * 64 + c * 16 + l16) * 64 + pb0 * 8];
            bf1[c] = *(const short8*)&Bb[(wn * 64 + c * 16 + l16) * 64 + pb1 * 8];
        }

        const bool pre = (it + 2 < nsteps);
        const int kk2 = kBase + (it + 2) * 64;
        if (pre) stagePart(st2, kk2, 0);

        __builtin_amdgcn_s_setprio(1);
#pragma unroll
        for (int r = 0; r < 4; ++r)
#pragma unroll
            for (int c = 0; c < 4; ++c)
                acc[r][c] = __builtin_amdgcn_mfma_f32_16x16x32_bf16(af0[r], bf0[c], acc[r][c], 0, 0, 0);
        __builtin_amdgcn_s_setprio(0);

        if (pre) stagePart(st2, kk2, 1);

        __builtin_amdgcn_s_setprio(1);
#pragma unroll
        for (int r = 0; r < 4; ++r)
#pragma unroll
            for (int c = 0; c < 4; ++c)
                acc[r][c] = __builtin_amdgcn_mfma_f32_16x16x32_bf16(af1[r], bf1[c], acc[r][c], 0, 0, 0);
        __builtin_amdgcn_s_setprio(0);

        st  = (st  == 2) ? 0 : st + 1;
        st2 = (st2 == 2) ? 0 : st2 + 1;
    }

    if (VT && col0 >= 2048) {
        // V section: write transposed into Vt[((n*16+h)*64+d)*1024 + k]
#pragma unroll
        for (int c = 0; c < 4; ++c) {
            const int col = col0 + wn * 64 + c * 16 + l16;
            const float bb = b2p[col & 1023];
            const int d = col & 63, hh = (col >> 6) & 15;
#pragma unroll
            for (int r = 0; r < 4; ++r) {
                const int row = row0 + wm * 64 + r * 16 + q * 4;
                const int nn = row >> 10, k = row & 1023;
                ushort4 o;
                o.x = f2bf(acc[r][c][0] + bb);
                o.y = f2bf(acc[r][c][1] + bb);
                o.z = f2bf(acc[r][c][2] + bb);
                o.w = f2bf(acc[r][c][3] + bb);
                *(ushort4*)&VtOut[((size_t)(nn * 16 + hh) * 64 + d) * 1024 + k] = o;
            }
        }
        return;
    }

    float* Pout = PARTIAL ? (blockIdx.z == 0 ? (float*)Cout : (float*)VtOut) : nullptr;

#pragma unroll
    for (int c = 0; c < 4; ++c) {
        const int col = col0 + wn * 64 + c * 16 + l16;
        float bb = 0.0f;
        if (!PARTIAL) {
            if (BIAS3) {
                const int sec = col >> 10;
                const float* bp = sec == 0 ? b0 : (sec == 1 ? b1p : b2p);
                bb = bp[col & 1023];
            } else {
                bb = b0[col];
            }
        }
#pragma unroll
        for (int r = 0; r < 4; ++r) {
#pragma unroll
            for (int reg = 0; reg < 4; ++reg) {
                const int row = row0 + wm * 64 + r * 16 + q * 4 + reg;
                float v = acc[r][c][reg] + bb;
                if (PARTIAL) {
                    Pout[(size_t)row * Nd + col] = acc[r][c][reg];
                } else {
                    if (RELU)  v = fmaxf(v, 0.0f);
                    if (RESID) v += resid[(size_t)row * Nd + col];
                    if (OUT_BF16) ((u16*)Cout)[(size_t)row * Nd + col] = f2bf(v);
                    else          ((float*)Cout)[(size_t)row * Nd + col] = v;
                }
            }
        }
    }
}

// ---------------------------------------------------------------------------
// MFMA flash attention v10b (SESSION BEST, round-17 verified 313.3 us):
// T14 reg-staged prefetch, full causal prefix, direct normalized output,
// P-HALF (PSTR 72, LDS 50 KB), __launch_bounds__(512,4) (no spill, VGPR 64).
// Round-19 refuted the KV-split cleanly: clean run (no spill) showed attn
// time unchanged at half work/block -- the barrier-lockstepped per-tile
// chain is the floor, not TLP. Reverted to this structure.
// LDS 51200 B. Grid (NH, SEQ/128, NB).
// ---------------------------------------------------------------------------
#define PSTR 72
#define ATTN_LDS (128*64*2 + 64*128*2 + 8*16*PSTR*2)   // 16K + 16K + 18432 = 51200

__global__ __launch_bounds__(512, 4) void attn_mfma(const u16* __restrict__ QKV,
                                                    const u16* __restrict__ Vt,
                                                    const int* __restrict__ cls,
                                                    const u32* __restrict__ bits,
                                                    u16* __restrict__ Yout) {
    const int h  = blockIdx.x;     // head -> determines XCD (b&7 = h&7)
    const int n  = blockIdx.z;
    const int qt = (n & 2) ? 7 - (int)blockIdx.y : (int)blockIdx.y;  // causal balance
    const int t  = threadIdx.x;
    const int wave = t >> 6;       // 0..7
    const int lane = t & 63;
    const int quad = lane >> 4;
    const int l16  = lane & 15;
    const int sw   = wave >> 2;    // q-subtile
    const int wq   = wave & 3;     // sub-wave slot within the subtile

    extern __shared__ __align__(16) char smem[];
    u16* Ks = (u16*)smem;                          // [key][d]  128x64, 16 KB
    u16* Vs = (u16*)(smem + 128 * 64 * 2);         // [d][key]  64x128, 16 KB
    u16* Pw = (u16*)(smem + 128 * 64 * 2 + 64 * 128 * 2) + wave * 16 * PSTR; // wave-private P (64 keys)

    const int bh = n * NH + h;
    const int i0 = qt * 128;

    // tile classes; actives form a prefix (causal) -> na block-uniform
    int cl[8];
    if (cls) {
        const int* cp = &cls[(n * 8 + qt) * 8];
#pragma unroll
        for (int j = 0; j < 8; ++j) cl[j] = cp[j];
    } else {
#pragma unroll
        for (int j = 0; j < 8; ++j) cl[j] = 2;
    }
    int na = 0;
#pragma unroll
    for (int j = 0; j < 8; ++j) if (cl[j] != 0) ++na;

    // Q A-fragment for this wave's 16 q-rows, pre-scaled by 0.125*log2e
    short8 qf[2];
    {
        const u16* qrow = QKV + ((size_t)n * SEQ + i0 + sw * 64 + wq * 16 + l16) * QS + h * 64 + quad * 8;
        short8 a = *(const short8*)(qrow);
        short8 b = *(const short8*)(qrow + 32);
#pragma unroll
        for (int j = 0; j < 8; ++j) {
            qf[0][j] = (short)f2bf(bf2f((u16)a[j]) * 0.18033688f);
            qf[1][j] = (short)f2bf(bf2f((u16)b[j]) * 0.18033688f);
        }
    }

    f32x4 O[4];
#pragma unroll
    for (int d = 0; d < 4; ++d) O[d] = (f32x4)0.0f;
    float lrow[4] = {};

    const int x7 = l16 & 7;

    // ---- T14 reg-staging maps (LDS content: Ks[r][c^(r&7)], Vs[r][c^(r&15)]) ----
    const int kr  = wave * 16 + (lane & 15);          // K row 0..127
    const int ck0 = (lane >> 4) * 2;                  // K col-blocks {ck0, ck0+1} of 8
    const int vr  = wave * 8 + (lane >> 3);           // V row 0..63
    const int cv0 = (lane & 7) * 2;                   // V col-blocks {cv0, cv0+1} of 16
    u16* kdst0 = &Ks[kr * 64 + ((ck0)     ^ (kr & 7)) * 8];
    u16* kdst1 = &Ks[kr * 64 + ((ck0 + 1) ^ (kr & 7)) * 8];
    u16* vdst0 = &Vs[vr * 128 + ((cv0)     ^ (vr & 15)) * 8];
    u16* vdst1 = &Vs[vr * 128 + ((cv0 + 1) ^ (vr & 15)) * 8];
    const u16* kgbase = QKV + ((size_t)n * SEQ + kr) * QS + 1024 + h * 64 + ck0 * 8;
    const u16* vgbase = Vt + ((size_t)bh * HD + vr) * SEQ + cv0 * 8;

    short8 krg0, krg1, vrg0, vrg1;
    auto loadT = [&](int j) {
        const u16* kp = kgbase + (size_t)j * 128 * QS;
        krg0 = *(const short8*)(kp);
        krg1 = *(const short8*)(kp + 8);
        const u16* vp = vgbase + j * 128;
        vrg0 = *(const short8*)(vp);
        vrg1 = *(const short8*)(vp + 8);
    };
    auto writeT = [&]() {
        *(short8*)kdst0 = krg0;
        *(short8*)kdst1 = krg1;
        *(short8*)vdst0 = vrg0;
        *(short8*)vdst1 = vrg1;
    };

    // prologue: stage tile 0 (always active: causal prefix includes j=0)
    loadT(0);
    writeT();
    asm volatile("s_waitcnt lgkmcnt(0)" ::: "memory");
    __builtin_amdgcn_s_barrier();          // tile-0 writes visible

    for (int j = 0; j < na; ++j) {
        const int c = cl[j];
        if (j + 1 < na) loadT(j + 1);      // in flight across the whole compute

        // ---- S = Q K^T ----
        f32x4 S[8];
#pragma unroll
        for (int sub = 0; sub < 8; ++sub) {
            S[sub] = (f32x4)0.0f;
            const int row = sub * 16 + l16;
            short8 k0 = *(const short8*)&Ks[row * 64 + ((quad ^ x7) * 8)];
            S[sub] = __builtin_amdgcn_mfma_f32_16x16x32_bf16(qf[0], k0, S[sub], 0, 0, 0);
            short8 k1 = *(const short8*)&Ks[row * 64 + (((4 + quad) ^ x7) * 8)];
            S[sub] = __builtin_amdgcn_mfma_f32_16x16x32_bf16(qf[1], k1, S[sub], 0, 0, 0);
        }

        if (c == 1) {
#pragma unroll
            for (int reg = 0; reg < 4; ++reg) {
                const int row = sw * 64 + wq * 16 + quad * 4 + reg;
                const uint4 mm = *(const uint4*)&bits[((size_t)((n * 8 + qt) * 8 + j) * 128 + row) * 4];
#pragma unroll
                for (int sub = 0; sub < 8; ++sub) {
                    const u32 seg = (sub >> 1) == 0 ? mm.x : (sub >> 1) == 1 ? mm.y : (sub >> 1) == 2 ? mm.z : mm.w;
                    if (!((seg >> ((sub & 1) * 16 + l16)) & 1u)) S[sub][reg] = -1e30f;
                }
            }
        }

        // ---- softmax + PV in two 64-key halves (P buffer holds 64 keys) ----
        float rst[4] = {0.0f, 0.0f, 0.0f, 0.0f};
#pragma unroll
        for (int h2 = 0; h2 < 2; ++h2) {
#pragma unroll
            for (int reg = 0; reg < 4; ++reg) {
#pragma unroll
                for (int s4 = 0; s4 < 4; ++s4) {
                    float e = exp2f(S[h2 * 4 + s4][reg]);    // masked: exp2(-1e30) = 0
                    Pw[(quad * 4 + reg) * PSTR + s4 * 16 + l16] = f2bf_trunc(e);
                    rst[reg] += e;
                }
            }
            short8 pa[2];
#pragma unroll
            for (int ks = 0; ks < 2; ++ks)
                pa[ks] = *(const short8*)&Pw[l16 * PSTR + ks * 32 + quad * 8];
#pragma unroll
            for (int d = 0; d < 4; ++d) {
                const int row = d * 16 + l16;
#pragma unroll
                for (int ks = 0; ks < 2; ++ks) {
                    const int kg = h2 * 2 + ks;
                    short8 vb = *(const short8*)&Vs[row * 128 + (((kg * 4 + quad) ^ l16) & 15) * 8];
                    O[d] = __builtin_amdgcn_mfma_f32_16x16x32_bf16(pa[ks], vb, O[d], 0, 0, 0);
                }
            }
        }
#pragma unroll
        for (int reg = 0; reg < 4; ++reg) {
            float rs = rst[reg];
            rs += __shfl_xor(rs, 1);
            rs += __shfl_xor(rs, 2);
            rs += __shfl_xor(rs, 4);
            rs += __shfl_xor(rs, 8);
            lrow[reg] += rs;
        }

        __builtin_amdgcn_s_barrier();      // all waves done READING tile j LDS
        if (j + 1 < na) {
            writeT();                      // compiler waits vmcnt on krg/vrg deps
            asm volatile("s_waitcnt lgkmcnt(0)" ::: "memory");
        }
        __builtin_amdgcn_s_barrier();      // tile j+1 writes visible
    }

    // ---- normalize + write into the consumed Q section ----
#pragma unroll
    for (int d = 0; d < 4; ++d) {
#pragma unroll
        for (int reg = 0; reg < 4; ++reg) {
            const int row = i0 + sw * 64 + wq * 16 + quad * 4 + reg;
            const int col = h * 64 + d * 16 + l16;
            Yout[((size_t)n * SEQ + row) * QS + col] = f2bf(O[d][reg] / lrow[reg]);
        }
    }
}

// ---------------------------------------------------------------------------
// Fused: LN( p0 + p1 + bias + resid ) -> fp32 out + optional bf16 out.
// In-place rule: Y/Yb may alias p0/p1/resid ROW-wise only.
// ---------------------------------------------------------------------------
__global__ __launch_bounds__(256) void ln_fused2(const float* __restrict__ p0,
                                                 const float* __restrict__ p1,
                                                 const float* __restrict__ bias,
                                                 const float* __restrict__ resid,
                                                 const float* __restrict__ g,
                                                 const float* __restrict__ be,
                                                 float* __restrict__ Y,
                                                 u16* __restrict__ Yb) {
    const int row = blockIdx.x;
    const int t = threadIdx.x;
    __shared__ float red[256];

    const float4 a = ((const float4*)(p0 + (size_t)row * MD))[t];
    const float4 b = ((const float4*)(p1 + (size_t)row * MD))[t];
    const float4 r = ((const float4*)(resid + (size_t)row * MD))[t];
    const float4 bi = ((const float4*)bias)[t];
    float4 v;
    v.x = a.x + b.x + r.x + bi.x;
    v.y = a.y + b.y + r.y + bi.y;
    v.z = a.z + b.z + r.z + bi.z;
    v.w = a.w + b.w + r.w + bi.w;

    red[t] = v.x + v.y + v.z + v.w;
    __syncthreads();
    for (int s2 = 128; s2 > 0; s2 >>= 1) {
        if (t < s2) red[t] += red[t + s2];
        __syncthreads();
    }
    const float mu = red[0] * (1.0f / MD);
    __syncthreads();

    float dx = v.x - mu, dy = v.y - mu, dz = v.z - mu, dw = v.w - mu;
    red[t] = dx * dx + dy * dy + dz * dz + dw * dw;
    __syncthreads();
    for (int s2 = 128; s2 > 0; s2 >>= 1) {
        if (t < s2) red[t] += red[t + s2];
        __syncthreads();
    }
    const float var = red[0] * (1.0f / MD);
    const float rs = rsqrtf(var + EPSF);

    const float4 gv = ((const float4*)g)[t];
    const float4 bv = ((const float4*)be)[t];
    float4 o;
    o.x = dx * rs * gv.x + bv.x;
    o.y = dy * rs * gv.y + bv.y;
    o.z = dz * rs * gv.z + bv.z;
    o.w = dw * rs * gv.w + bv.w;
    if (Y) ((float4*)(Y + (size_t)row * MD))[t] = o;
    if (Yb) {
        ushort4 ob;
        ob.x = f2bf(o.x); ob.y = f2bf(o.y); ob.z = f2bf(o.z); ob.w = f2bf(o.w);
        ((ushort4*)(Yb + (size_t)row * MD))[t] = ob;
    }
}

// ---------------------------------------------------------------------------
extern "C" void kernel_launch(void* const* d_in, const int* in_sizes, int n_in,
                              void* d_out, int out_size, void* d_ws, size_t ws_size,
                              hipStream_t stream) {
    const float* dec  = (const float*)d_in[0];
    const float* enc  = (const float*)d_in[1];
    const int*   mask = (const int*)d_in[2];
    const float* Wq_s = (const float*)d_in[3];
    const float* bq_s = (const float*)d_in[4];
    const float* Wk_s = (const float*)d_in[5];
    const float* bk_s = (const float*)d_in[6];
    const float* Wv_s = (const float*)d_in[7];
    const float* bv_s = (const float*)d_in[8];
    const float* Wo_s = (const float*)d_in[9];
    const float* bo_s = (const float*)d_in[10];
    const float* Wq_c = (const float*)d_in[11];
    const float* bq_c = (const float*)d_in[12];
    const float* Wk_c = (const float*)d_in[13];
    const float* bk_c = (const float*)d_in[14];
    const float* Wv_c = (const float*)d_in[15];
    const float* bv_c = (const float*)d_in[16];
    const float* Wo_c = (const float*)d_in[17];
    const float* bo_c = (const float*)d_in[18];
    const float* W1   = (const float*)d_in[19];
    const float* b1   = (const float*)d_in[20];
    const float* W2   = (const float*)d_in[21];
    const float* b2   = (const float*)d_in[22];
    const float* g1   = (const float*)d_in[23];
    const float* be1  = (const float*)d_in[24];
    const float* g2   = (const float*)d_in[25];
    const float* be2  = (const float*)d_in[26];
    const float* g3   = (const float*)d_in[27];
    const float* be3  = (const float*)d_in[28];

    char* wsb = (char*)d_ws;
    const size_t MB = 1u << 20;
    u16*   decb  = (u16*)(wsb + 0 * MB);
    u16*   O2b   = (u16*)(wsb + 0 * MB);
    u16*   encb  = (u16*)(wsb + 8 * MB);
    u16*   WqkvsT= (u16*)(wsb + 16 * MB);
    u16*   WqkvcT= (u16*)(wsb + 22 * MB);
    u16*   WosT  = (u16*)(wsb + 28 * MB);
    u16*   WocT  = (u16*)(wsb + 30 * MB);
    u16*   W1T   = (u16*)(wsb + 32 * MB);
    u16*   W2T   = (u16*)(wsb + 40 * MB);
    u16*   QKVb  = (u16*)(wsb + 48 * MB);
    u16*   Vt    = (u16*)(wsb + 72 * MB);
    u16*   Hb    = (u16*)(wsb + 48 * MB);
    int*   mcls  = (int*)(wsb + 80 * MB);
    u32*   mbits = (u32*)(wsb + 80 * MB + 64 * 1024);
    float* P0    = (float*)(wsb + 80 * MB);    // Wo partial 0 (both passes)
    float* O2    = (float*)(wsb + 96 * MB);    // p1-self lands here, LN1 in-place
    float* O4    = (float*)(wsb + 96 * MB);    // LN2 in-place over O2
    float* P1c   = (float*)(wsb + 0 * MB);     // Wo-cross partial 1
    u16*   O4b   = (u16*)(wsb + 16 * MB);
    float* FP    = (float*)(wsb + 0 * MB);     // FFN2 partials: z0 0-16, z1 16-32

    dim3 blk(256);
    dim3 blkA(512);
    dim3 blkG(512);
    dim3 gConv(NK * MD / 4 / 256, 2);
    dim3 gMask(8, 8, 4);
    dim3 gQkvW(16, 16, 6);
    dim3 gFlatW(16, 16, 10);
    dim3 gAttn(NH, SEQ / 128, NB);           // x=h -> XCD=h&7
    dim3 gQKV(QS / 128, NK / 256);           // (24,16): swzW=6
    dim3 gWo(MD / 128, NK / 256, 2);         // (8,16,2): Wo SK=2, full chip
    dim3 gF1(FF / 128, NK / 256);            // (32,16): swzW=8
    dim3 gF2(MD / 128, NK / 256, 2);         // (8,16,2): swzW=2
    const int GP_LDS = 3 * (256 * 64 + 128 * 64) * 2;   // 144 KB (3-slot pipeline)

    // ---- converts + repacks + mask precompute ----
    conv_bf16<<<gConv, blk, 0, stream>>>(dec, enc, decb, encb);
    mask_tiles<<<gMask, blk, 0, stream>>>(mask, mcls, mbits);

    QkvArgs qa;
    qa.src[0] = Wq_s; qa.src[1] = Wk_s; qa.src[2] = Wv_s;
    qa.src[3] = Wq_c; qa.src[4] = Wk_c; qa.src[5] = Wv_c;
    qa.dst[0] = WqkvsT;                 qa.dst[1] = WqkvsT + (size_t)1024 * 1024;
    qa.dst[2] = WqkvsT + (size_t)2048 * 1024;
    qa.dst[3] = WqkvcT;                 qa.dst[4] = WqkvcT + (size_t)1024 * 1024;
    qa.dst[5] = WqkvcT + (size_t)2048 * 1024;
    repack_qkv<<<gQkvW, blk, 0, stream>>>(qa);

    FlatArgs fa;
    fa.d[0] = { Wo_s, 1024, WosT, 1024 };
    fa.d[1] = { Wo_c, 1024, WocT, 1024 };
    for (int u = 0; u < 4; ++u)
        fa.d[2 + u] = { W1 + (size_t)u * 1024, 4096, W1T + (size_t)u * 1024 * 1024, 1024 };
    for (int u = 0; u < 4; ++u)
        fa.d[6 + u] = { W2 + (size_t)u * 1024 * 1024, 1024, W2T + (size_t)u * 1024, 4096 };
    repack_flat<<<gFlatW, blk, 0, stream>>>(fa);

    // ---- self attention ----
    gemm256p<1, 0, 1, 0, 1, 0><<<gQKV, blkG, GP_LDS, stream>>>(decb, decb, MD, WqkvsT, MD, bq_s, bk_s, bv_s, nullptr, QKVb, Vt, MD, QS, 6);
    attn_mfma<<<gAttn, blkA, ATTN_LDS, stream>>>(QKVb, Vt, mcls, mbits, QKVb);
    gemm256p<0, 0, 0, 1, 0, 0><<<gWo, blkG, GP_LDS, stream>>>(QKVb, QKVb, QS, WosT, MD, nullptr, nullptr, nullptr, nullptr, P0, (u16*)O2, MD / 2, MD, 2);
    ln_fused2<<<NK, blk, 0, stream>>>(P0, O2, bo_s, dec, g1, be1, O2, O2b);   // in-place over p1

    // ---- cross attention ----
    gemm256p<1, 0, 1, 0, 1, 0><<<gQKV, blkG, GP_LDS, stream>>>(O2b, encb, MD, WqkvcT, MD, bq_c, bk_c, bv_c, nullptr, QKVb, Vt, MD, QS, 6);
    attn_mfma<<<gAttn, blkA, ATTN_LDS, stream>>>(QKVb, Vt, nullptr, nullptr, QKVb);
    gemm256p<0, 0, 0, 1, 0, 0><<<gWo, blkG, GP_LDS, stream>>>(QKVb, QKVb, QS, WocT, MD, nullptr, nullptr, nullptr, nullptr, P0, (u16*)P1c, MD / 2, MD, 2);
    ln_fused2<<<NK, blk, 0, stream>>>(P0, P1c, bo_c, O2, g2, be2, O4, O4b);  // Y in-place over resid

    // ---- feed-forward (FFN2 split-K=2; epilogue fused into LN) ----
    gemm256p<1, 1, 0, 0, 0, 0><<<gF1, blkG, GP_LDS, stream>>>(O4b, O4b, MD, W1T, MD, b1, nullptr, nullptr, nullptr, Hb, nullptr, MD, FF, 8);
    gemm256p<0, 0, 0, 1, 0, 0><<<gF2, blkG, GP_LDS, stream>>>(Hb, Hb, FF, W2T, FF, nullptr, nullptr, nullptr, nullptr, FP, (u16*)(FP + (size_t)NK * MD), FF / 2, MD, 2);
    ln_fused2<<<NK, blk, 0, stream>>>(FP, FP + (size_t)NK * MD, b2, O4, g3, be3, (float*)d_out, nullptr);
}